// Round 1
// baseline (14.477 us; speedup 1.0000x reference)
//
#include <hip/hip_runtime.h>

// Bone/variance loss: B samples -> scalar.
// output: [B,1,64,64] f32, mask: [B,17] f32, ind: [B,17] int, target: [B,17] f32, gt_2d: [B,17,2] f32
// out: [1] f32

__global__ __launch_bounds__(256) void bone_partial(
    const float* __restrict__ out_hm,
    const float* __restrict__ mask,
    const int*   __restrict__ ind,
    const float* __restrict__ target,
    const float* __restrict__ gt2d,
    float* __restrict__ partial, int B)
{
    constexpr int id1[12]  = {3, 2, 4, 5, 16, 15, 11, 12, 1, 4, 14, 11};
    constexpr int id2[12]  = {2, 1, 5, 6, 15, 14, 12, 13, 0, 0,  8,  8};
    constexpr int gid[12]  = {0, 0, 0, 0,  1,  1,  1,  1, 2, 2,  3,  3};
    const float wbone[12]  = {1.0085885098415446f, 1.0f, 1.0f, 1.0085885098415446f,
                              1.1375361376887123f, 1.0f, 1.0f, 1.1375361376887123f,
                              1.0f, 1.0f, 1.0f, 1.0f};

    const int b = blockIdx.x * blockDim.x + threadIdx.x;
    float per = 0.0f;
    if (b < B) {
        const float*  tb = target + (size_t)b * 17;
        const float*  mb = mask   + (size_t)b * 17;
        const int*    ib = ind    + (size_t)b * 17;
        const float2* gb = (const float2*)(gt2d + (size_t)b * 34);
        const float*  ob = out_hm + (size_t)b * 4096;

        float msum = 0.0f;
        float t[17], gx[17], gy[17], pr[17];
        #pragma unroll
        for (int j = 0; j < 17; ++j) msum += mb[j];
        #pragma unroll
        for (int j = 0; j < 17; ++j) t[j] = tb[j];
        #pragma unroll
        for (int j = 0; j < 17; ++j) { float2 g = gb[j]; gx[j] = g.x; gy[j] = g.y; }
        #pragma unroll
        for (int j = 0; j < 17; ++j) pr[j] = ob[ib[j]];

        float num[4] = {0,0,0,0}, sl[4] = {0,0,0,0};
        float l[12];
        bool  vis[12];
        #pragma unroll
        for (int k = 0; k < 12; ++k) {
            const int a = id1[k], c = id2[k];
            const bool v = (t[a] > 0.5f) && (t[c] > 0.5f);
            const float dx = gx[a] - gx[c];
            const float dy = gy[a] - gy[c];
            const float dp = pr[a] - pr[c];
            const float d2 = dx*dx + dy*dy + dp*dp;
            const float lv = v ? sqrtf(d2) * wbone[k] : 0.0f;
            vis[k] = v; l[k] = lv;
            num[gid[k]] += v ? 1.0f : 0.0f;
            sl[gid[k]]  += lv;
        }
        float E[4], dn[4];
        #pragma unroll
        for (int g = 0; g < 4; ++g) { dn[g] = fmaxf(num[g], 1.0f); E[g] = sl[g] / dn[g]; }
        #pragma unroll
        for (int k = 0; k < 12; ++k) {
            if (vis[k] && l[k] > 0.0f) {
                const float d = l[k] - E[gid[k]];
                per += d * d / (2.0f * dn[gid[k]]);
            }
        }
        if (msum != 0.0f) per = 0.0f;   // active = (mask.sum == 0)
    }

    // deterministic block reduction: wave64 shfl -> LDS across waves
    #pragma unroll
    for (int off = 32; off > 0; off >>= 1) per += __shfl_down(per, off, 64);
    __shared__ float smem[8];
    const int lane = threadIdx.x & 63;
    const int wid  = threadIdx.x >> 6;
    if (lane == 0) smem[wid] = per;
    __syncthreads();
    if (threadIdx.x == 0) {
        float s = 0.0f;
        const int nw = (blockDim.x + 63) >> 6;
        for (int i = 0; i < nw; ++i) s += smem[i];
        partial[blockIdx.x] = s;
    }
}

__global__ void bone_finalize(const float* __restrict__ partial, int n,
                              float* __restrict__ out, float invB)
{
    if (blockIdx.x == 0 && threadIdx.x == 0) {
        float s = 0.0f;
        for (int i = 0; i < n; ++i) s += partial[i];
        out[0] = s * invB;   // _VAR_WEIGHT == 1.0
    }
}

extern "C" void kernel_launch(void* const* d_in, const int* in_sizes, int n_in,
                              void* d_out, int out_size, void* d_ws, size_t ws_size,
                              hipStream_t stream)
{
    const float* output = (const float*)d_in[0];
    const float* mask   = (const float*)d_in[1];
    const int*   ind    = (const int*)  d_in[2];
    const float* target = (const float*)d_in[3];
    const float* gt2d   = (const float*)d_in[4];

    const int B    = in_sizes[1] / 17;        // mask is [B,17]
    const int nblk = (B + 255) / 256;

    float* partial = (float*)d_ws;            // nblk floats of scratch

    bone_partial<<<nblk, 256, 0, stream>>>(output, mask, ind, target, gt2d, partial, B);
    bone_finalize<<<1, 1, 0, stream>>>(partial, nblk, (float*)d_out, 1.0f / (float)B);
}

// Round 2
// 10.953 us; speedup vs baseline: 1.3217x; 1.3217x over previous
//
#include <hip/hip_runtime.h>

// Bone/variance loss: B samples -> scalar.
// output: [B,1,64,64] f32, mask: [B,17] f32, ind: [B,17] int32, target: [B,17] f32, gt_2d: [B,17,2] f32
// out: [1] f32
//
// Round 2: 64-thread blocks (1 wave) x 128 blocks -> 4x CU coverage vs round 1
// (latency-bound gather kernel), pure-shfl block reduction, wave-parallel finalize.

#define BLK 64

__global__ __launch_bounds__(BLK) void bone_partial(
    const float* __restrict__ out_hm,
    const float* __restrict__ mask,
    const int*   __restrict__ ind,
    const float* __restrict__ target,
    const float* __restrict__ gt2d,
    float* __restrict__ partial, int B)
{
    constexpr int id1[12]  = {3, 2, 4, 5, 16, 15, 11, 12, 1, 4, 14, 11};
    constexpr int id2[12]  = {2, 1, 5, 6, 15, 14, 12, 13, 0, 0,  8,  8};
    constexpr int gid[12]  = {0, 0, 0, 0,  1,  1,  1,  1, 2, 2,  3,  3};
    const float wbone[12]  = {1.0085885098415446f, 1.0f, 1.0f, 1.0085885098415446f,
                              1.1375361376887123f, 1.0f, 1.0f, 1.1375361376887123f,
                              1.0f, 1.0f, 1.0f, 1.0f};

    const int b = blockIdx.x * BLK + threadIdx.x;
    float per = 0.0f;
    if (b < B) {
        const float*  tb = target + (size_t)b * 17;
        const float*  mb = mask   + (size_t)b * 17;
        const int*    ib = ind    + (size_t)b * 17;
        const float2* gb = (const float2*)(gt2d + (size_t)b * 34);
        const float*  ob = out_hm + (size_t)b * 4096;

        // Issue the long-latency random gathers first.
        int   idx[17];
        #pragma unroll
        for (int j = 0; j < 17; ++j) idx[j] = ib[j];
        float pr[17];
        #pragma unroll
        for (int j = 0; j < 17; ++j) pr[j] = ob[idx[j]];

        float t[17], gx[17], gy[17];
        #pragma unroll
        for (int j = 0; j < 17; ++j) t[j] = tb[j];
        #pragma unroll
        for (int j = 0; j < 17; ++j) { float2 g = gb[j]; gx[j] = g.x; gy[j] = g.y; }
        float msum = 0.0f;
        #pragma unroll
        for (int j = 0; j < 17; ++j) msum += mb[j];

        float num[4] = {0,0,0,0}, sl[4] = {0,0,0,0};
        float l[12];
        bool  vis[12];
        #pragma unroll
        for (int k = 0; k < 12; ++k) {
            const int a = id1[k], c = id2[k];
            const bool v = (t[a] > 0.5f) && (t[c] > 0.5f);
            const float dx = gx[a] - gx[c];
            const float dy = gy[a] - gy[c];
            const float dp = pr[a] - pr[c];
            const float d2 = dx*dx + dy*dy + dp*dp;
            const float lv = v ? sqrtf(d2) * wbone[k] : 0.0f;
            vis[k] = v; l[k] = lv;
            num[gid[k]] += v ? 1.0f : 0.0f;
            sl[gid[k]]  += lv;
        }
        float E[4], dn[4];
        #pragma unroll
        for (int g = 0; g < 4; ++g) { dn[g] = fmaxf(num[g], 1.0f); E[g] = sl[g] / dn[g]; }
        #pragma unroll
        for (int k = 0; k < 12; ++k) {
            if (vis[k] && l[k] > 0.0f) {
                const float d = l[k] - E[gid[k]];
                per += d * d / (2.0f * dn[gid[k]]);
            }
        }
        if (msum != 0.0f) per = 0.0f;   // active = (mask.sum == 0)
    }

    // single-wave block: pure shuffle reduction, no LDS, no barrier
    #pragma unroll
    for (int off = 32; off > 0; off >>= 1) per += __shfl_down(per, off, 64);
    if (threadIdx.x == 0) partial[blockIdx.x] = per;
}

__global__ __launch_bounds__(64) void bone_finalize(
    const float* __restrict__ partial, int n,
    float* __restrict__ out, float invB)
{
    float s = 0.0f;
    for (int i = threadIdx.x; i < n; i += 64) s += partial[i];
    #pragma unroll
    for (int off = 32; off > 0; off >>= 1) s += __shfl_down(s, off, 64);
    if (threadIdx.x == 0) out[0] = s * invB;   // _VAR_WEIGHT == 1.0
}

extern "C" void kernel_launch(void* const* d_in, const int* in_sizes, int n_in,
                              void* d_out, int out_size, void* d_ws, size_t ws_size,
                              hipStream_t stream)
{
    const float* output = (const float*)d_in[0];
    const float* mask   = (const float*)d_in[1];
    const int*   ind    = (const int*)  d_in[2];
    const float* target = (const float*)d_in[3];
    const float* gt2d   = (const float*)d_in[4];

    const int B    = in_sizes[1] / 17;        // mask is [B,17]
    const int nblk = (B + BLK - 1) / BLK;     // 128 blocks for B=8192

    float* partial = (float*)d_ws;            // nblk floats of scratch

    bone_partial<<<nblk, BLK, 0, stream>>>(output, mask, ind, target, gt2d, partial, B);
    bone_finalize<<<1, 64, 0, stream>>>(partial, nblk, (float*)d_out, 1.0f / (float)B);
}